// Round 6
// baseline (746.681 us; speedup 1.0000x reference)
//
#include <hip/hip_runtime.h>
#include <hip/hip_fp16.h>

#define B_    256
#define CIN   128
#define CH    64
#define NPX   1024   // 32*32
#define NWIN  49
#define TROWS 22     // 16 tile rows + 3 halo each side
#define TCOLS 40     // 32 cols + 4 halo each side
#define NEG_INF_F (-1e30f)

typedef _Float16 h2v __attribute__((ext_vector_type(2)));
typedef __fp16   p2v __attribute__((ext_vector_type(2)));   // cvt_pkrtz result type

#if __has_builtin(__builtin_amdgcn_fdot2)
#define FDOT2(a, b, c) __builtin_amdgcn_fdot2((a), (b), (c), false)
#else
#define FDOT2(a, b, c) fmaf((float)(a)[0], (float)(b)[0], fmaf((float)(a)[1], (float)(b)[1], (c)))
#endif

union CV { p2v p; h2v h; uint u; };
union U8 { int4 v4[2]; uint u[8]; h2v h[8]; };

// acc(f32) += f16(vu, half vh) * f16(pu, half ph) — one v_fma_mix_f32.
#define FMIX(acc, vu, vh, pu, ph) do {                                                                              \
    if      ((vh) == 0 && (ph) == 0) asm("v_fma_mix_f32 %0, %1, %2, %0 op_sel:[0,0,0] op_sel_hi:[1,1,0]" : "+v"(acc) : "v"(vu), "v"(pu)); \
    else if ((vh) == 1 && (ph) == 0) asm("v_fma_mix_f32 %0, %1, %2, %0 op_sel:[1,0,0] op_sel_hi:[1,1,0]" : "+v"(acc) : "v"(vu), "v"(pu)); \
    else if ((vh) == 0 && (ph) == 1) asm("v_fma_mix_f32 %0, %1, %2, %0 op_sel:[0,1,0] op_sel_hi:[1,1,0]" : "+v"(acc) : "v"(vu), "v"(pu)); \
    else                             asm("v_fma_mix_f32 %0, %1, %2, %0 op_sel:[1,1,0] op_sel_hi:[1,1,0]" : "+v"(acc) : "v"(vu), "v"(pu)); \
} while (0)

// ---------------------------------------------------------------------------
// Pack W (Ch x Cin) -> pair-interleaved f16: WtP[i2*64 + o] = {W[o][2i2], W[o][2i2+1]}
// so conv's weight reads are uniform scalar loads feeding v_dot2_f32_f16.
// Also resolves same_WqWk on device.
// ---------------------------------------------------------------------------
__global__ __launch_bounds__(256) void wtrans_kernel(
    const float* __restrict__ Wq, const float* __restrict__ Wk,
    const int* __restrict__ same_flag,
    uint* __restrict__ WtPQ, uint* __restrict__ WtPK)
{
    const float* Wsel = (same_flag[0] != 0) ? Wq : Wk;
    for (int idx = threadIdx.x; idx < (CIN / 2) * CH; idx += 256) {
        int i2 = idx >> 6;   // input-channel pair 0..63
        int o  = idx & 63;   // output channel
        CV a; a.p = __builtin_amdgcn_cvt_pkrtz(Wq[o * CIN + 2 * i2], Wq[o * CIN + 2 * i2 + 1]);
        WtPQ[idx] = a.u;
        CV b2; b2.p = __builtin_amdgcn_cvt_pkrtz(Wsel[o * CIN + 2 * i2], Wsel[o * CIN + 2 * i2 + 1]);
        WtPK[idx] = b2.u;
    }
}

// ---------------------------------------------------------------------------
// All three 1x1 convs (blockIdx.y = 0:Q(left) 1:K(left) 2:K(right)) with
// v_dot2_f32_f16: x pair converted on the fly, W pre-packed (sgpr loads).
// 4096 dot2 (2 MAC/instr) vs 8192 fma. Output pair-packed f16 uints.
// ---------------------------------------------------------------------------
__global__ __launch_bounds__(256, 4) void conv3_kernel(
    const float* __restrict__ left, const float* __restrict__ right,
    const uint* __restrict__ WtPQ, const uint* __restrict__ WtPK,
    const float* __restrict__ bq, const float* __restrict__ bk,
    const int* __restrict__ same_flag,
    uint* __restrict__ dQ, uint* __restrict__ dKL, uint* __restrict__ dKR)
{
    int which = blockIdx.y;
    const float* x    = (which == 2) ? right : left;
    const uint*  Wt   = (which == 0) ? WtPQ : WtPK;
    const float* bias = (which == 0 || same_flag[0] != 0) ? bq : bk;
    uint* dst         = (which == 0) ? dQ : ((which == 1) ? dKL : dKR);

    int b  = blockIdx.x >> 2;
    int px = ((blockIdx.x & 3) << 8) + threadIdx.x;
    const float* xb = x + (size_t)b * (CIN * NPX) + px;

    float acc[CH];
#pragma unroll
    for (int o = 0; o < CH; ++o) acc[o] = bias[o];

#pragma unroll 4
    for (int i2 = 0; i2 < CIN / 2; ++i2) {
        float x0 = xb[(size_t)(2 * i2) << 10];
        float x1 = xb[(size_t)(2 * i2 + 1) << 10];
        CV xp; xp.p = __builtin_amdgcn_cvt_pkrtz(x0, x1);
        const uint* wrow = Wt + (i2 << 6);
#pragma unroll
        for (int o = 0; o < CH; ++o) {
            CV wv; wv.u = wrow[o];
            acc[o] = FDOT2(xp.h, wv.h, acc[o]);
        }
    }

    uint* db = dst + (size_t)b * ((CH / 2) * NPX) + px;
#pragma unroll
    for (int o2 = 0; o2 < CH / 2; ++o2) {
        CV cv; cv.p = __builtin_amdgcn_cvt_pkrtz(acc[2 * o2], acc[2 * o2 + 1]);
        db[(size_t)o2 << 10] = cv.u;
    }
}

// ---------------------------------------------------------------------------
// One score pass for pixel row (h+P). Only ONE sc[49] live -> ~85 regs peak,
// no AGPR shuffling, free regs for ds_read pipelining. 16-ch groups, b128 taps.
// ---------------------------------------------------------------------------
template<int P>
__device__ __forceinline__ void score_pass(
    const uint* __restrict__ Kb, const uint* __restrict__ Qb, uint* buf,
    int h, int w, int r2, int vp, int go_base, int li_base, uint* PH)
{
    float sc[NWIN];
#pragma unroll
    for (int i = 0; i < NWIN; ++i) sc[i] = 0.f;

    const int qoffP = ((h + P) << 5) + w;

    for (int g = 0; g < 4; ++g) {
        __syncthreads();
        {
            const uint* Ks = Kb + ((size_t)((g << 3) + vp) << 10) + go_base;
            int li = li_base;
#pragma unroll
            for (int i = 0; i < 19; ++i) {
                buf[li] = Ks[i << 5];
                li += TCOLS * 8;
            }
        }
        __syncthreads();

        CV qp[8];
#pragma unroll
        for (int j = 0; j < 8; ++j)
            qp[j].u = Qb[((size_t)((g << 3) + j) << 10) + qoffP];

#pragma unroll
        for (int dh = 0; dh < 7; ++dh) {
            int cu0 = ((r2 + P + dh) * TCOLS + (w + 1)) * 8;
#pragma unroll
            for (int dw = 0; dw < 7; ++dw) {
                U8 kk;
                kk.v4[0] = *(const int4*)(buf + cu0 + dw * 8);
                kk.v4[1] = *(const int4*)(buf + cu0 + dw * 8 + 4);
                float s = sc[dh * 7 + dw];
#pragma unroll
                for (int j = 0; j < 8; ++j) s = FDOT2(kk.h[j], qp[j].h, s);
                sc[dh * 7 + dw] = s;
            }
        }
    }

    // masked softmax (identical semantics to reference) + pack to f16 pairs
    const int hp = h + P;
    float m = NEG_INF_F;
#pragma unroll
    for (int dh = 0; dh < 7; ++dh)
#pragma unroll
        for (int dw = 0; dw < 7; ++dw) {
            int i = dh * 7 + dw;
            bool vld = ((unsigned)(hp + dh - 3) < 32u) && ((unsigned)(w + dw - 3) < 32u);
            sc[i] = vld ? sc[i] : NEG_INF_F;
            m = fmaxf(m, sc[i]);
        }
    float ssum = 0.f;
#pragma unroll
    for (int i = 0; i < NWIN; ++i) { sc[i] = __expf(sc[i] - m); ssum += sc[i]; }
    float inv = 1.f / ssum;
#pragma unroll
    for (int j = 0; j < 24; ++j) {
        CV cv; cv.p = __builtin_amdgcn_cvt_pkrtz(sc[2 * j] * inv, sc[2 * j + 1] * inv);
        PH[j] = cv.u;
    }
    CV cv; cv.p = __builtin_amdgcn_cvt_pkrtz(sc[48] * inv, 0.f);
    PH[24] = cv.u;
}

// ---------------------------------------------------------------------------
// Merged fused local attention (both sides via blockIdx.y). 16-row tile,
// 2 vertical px/thread. LDS [22 rows][40 cols][16 ch] f16 = 28160 B.
// Phase A: two sequential score passes (reg-friendly). Phase C: taps shared
// between the 2 px, FMIX f32 accumulation, 16-ch groups.
// ---------------------------------------------------------------------------
__global__ __launch_bounds__(256, 4) void attend2_kernel(
    const uint* __restrict__ Q, const uint* __restrict__ KR,
    const uint* __restrict__ KL,
    const float* __restrict__ right, const float* __restrict__ left,
    float* __restrict__ out, const int* __restrict__ self_flag)
{
    __shared__ __align__(16) uint buf[TROWS * TCOLS * 8];   // 28160 B

    int side = blockIdx.y;            // 0: right-attend, 1: left-attend
    int b    = blockIdx.x >> 1;
    int h0   = (blockIdx.x & 1) << 4;
    int t    = threadIdx.x;
    int w    = t & 31;
    int r2   = (t >> 5) << 1;         // 0,2,..,14
    int h    = h0 + r2;               // rows h and h+1
    int qoff = (h << 5) + w;
    int cb   = side ? 0 : CIN;

    const uint*  K = side ? KL : KR;
    const float* V = side ? left : right;

    if (side == 1 && self_flag[0] == 0) {
        const float* s = left + (size_t)b * (CIN * NPX) + qoff;
        float* d = out + (size_t)b * (2 * CIN * NPX) + qoff;
        for (int c = 0; c < CIN; ++c) {
            d[(size_t)c << 10] = s[(size_t)c << 10];
            d[((size_t)c << 10) + 32] = s[((size_t)c << 10) + 32];
        }
        return;
    }

    // ---- zero-fill LDS once (borders stay 0 through A and C) ----
#pragma unroll
    for (int i = 0; i < 7; ++i) {
        int idx = t + (i << 8);
        if (idx < TROWS * TCOLS * 2) ((int4*)buf)[idx] = int4{0, 0, 0, 0};
    }

    // staging geometry: 19 valid rows x 32 cols x 8 ch-pairs = 256 thr x 19
    int rowlo = (h0 == 0) ? 0 : h0 - 3;   // first valid global row
    int rowof = (h0 == 0) ? 3 : 0;        // its LDS row
    int vp    = t >> 5;                   // this thread's channel-pair 0..7
    int go_base = (rowlo << 5) + w;
    int li_base = (rowof * TCOLS + (w + 4)) * 8 + vp;

    const uint* Kb = K + (size_t)b * ((CH / 2) * NPX);
    const uint* Qb = Q + (size_t)b * ((CH / 2) * NPX);

    // ---- Phase A: two sequential passes ----
    uint ph0[25], ph1[25];
    score_pass<0>(Kb, Qb, buf, h, w, r2, vp, go_base, li_base, ph0);
    score_pass<1>(Kb, Qb, buf, h, w, r2, vp, go_base, li_base, ph1);

    // ---- Phase C: 8 groups of 16 channels, taps shared between px0/px1 ----
    const float* Vb = V + (size_t)b * (CIN * NPX);
    float* ob = out + (size_t)b * (2 * CIN * NPX) + ((size_t)cb << 10) + qoff;

    for (int vg = 0; vg < 8; ++vg) {
        __syncthreads();
        {
            const float* va = Vb + ((size_t)((vg << 4) + (vp << 1)) << 10);
            const float* vc = va + NPX;
            int li = li_base;
#pragma unroll
            for (int i = 0; i < 19; ++i) {
                int gi = go_base + (i << 5);
                CV cv; cv.p = __builtin_amdgcn_cvt_pkrtz(va[gi], vc[gi]);
                buf[li] = cv.u;
                li += TCOLS * 8;
            }
        }
        __syncthreads();

        float a0[16], a1[16];
#pragma unroll
        for (int c = 0; c < 16; ++c) { a0[c] = 0.f; a1[c] = 0.f; }

#pragma unroll
        for (int dh = 0; dh < 8; ++dh) {
            int cu0 = ((r2 + dh) * TCOLS + (w + 1)) * 8;
#pragma unroll
            for (int dw = 0; dw < 7; ++dw) {
                U8 kk;
                kk.v4[0] = *(const int4*)(buf + cu0 + dw * 8);
                kk.v4[1] = *(const int4*)(buf + cu0 + dw * 8 + 4);
                if (dh < 7) {
                    int tp = dh * 7 + dw;
#pragma unroll
                    for (int c = 0; c < 16; ++c)
                        FMIX(a0[c], kk.u[c >> 1], (c & 1), ph0[tp >> 1], (tp & 1));
                }
                if (dh >= 1) {
                    int tp = (dh - 1) * 7 + dw;
#pragma unroll
                    for (int c = 0; c < 16; ++c)
                        FMIX(a1[c], kk.u[c >> 1], (c & 1), ph1[tp >> 1], (tp & 1));
                }
            }
        }
#pragma unroll
        for (int c = 0; c < 16; ++c) {
            ob[((size_t)((vg << 4) + c)) << 10] = a0[c];
            ob[(((size_t)((vg << 4) + c)) << 10) + 32] = a1[c];
        }
    }
}

// ---------------------------------------------------------------------------
// 3 launches: wtrans -> conv3 (3072 blocks) -> attend2 (1024 blocks).
// ws: 3 x 32 MiB pair-packed f16 (Q, K_left, K_right) + 2 packed W = 96.03 MiB.
// ---------------------------------------------------------------------------
extern "C" void kernel_launch(void* const* d_in, const int* in_sizes, int n_in,
                              void* d_out, int out_size, void* d_ws, size_t ws_size,
                              hipStream_t stream)
{
    (void)in_sizes; (void)n_in; (void)out_size; (void)ws_size;

    const float* left  = (const float*)d_in[0];
    const float* right = (const float*)d_in[1];
    const float* Wq    = (const float*)d_in[2];
    const float* bq    = (const float*)d_in[3];
    const float* Wk    = (const float*)d_in[4];
    const float* bk    = (const float*)d_in[5];
    const int* self_flag = (const int*)d_in[7];
    const int* same_flag = (const int*)d_in[8];

    uint* wsQ  = (uint*)d_ws;                              // 32 MiB
    uint* wsKL = wsQ  + (size_t)B_ * (CH / 2) * NPX;       // 32 MiB
    uint* wsKR = wsKL + (size_t)B_ * (CH / 2) * NPX;       // 32 MiB
    uint* WtPQ = wsKR + (size_t)B_ * (CH / 2) * NPX;       // 4096 uints
    uint* WtPK = WtPQ + (CIN / 2) * CH;

    float* out = (float*)d_out;

    wtrans_kernel<<<1, 256, 0, stream>>>(Wq, Wk, same_flag, WtPQ, WtPK);

    conv3_kernel<<<dim3(B_ * 4, 3), 256, 0, stream>>>(
        left, right, WtPQ, WtPK, bq, bk, same_flag, wsQ, wsKL, wsKR);

    attend2_kernel<<<dim3(B_ * 2, 2), 256, 0, stream>>>(
        wsQ, wsKR, wsKL, right, left, out, self_flag);
}

// Round 7
// 343.560 us; speedup vs baseline: 2.1734x; 2.1734x over previous
//
#include <hip/hip_runtime.h>
#include <hip/hip_fp16.h>

#define B_    256
#define CIN   128
#define CH    64
#define NPX   1024   // 32*32
#define NWIN  49
#define TROWS 22     // 16 tile rows + 3 halo each side
#define TCOLS 40     // 32 cols + 4 halo each side
#define CELLU 4      // uints per cell = 8 f16 channels = 16 B (benign 8-way banking)
#define BUFU  (TROWS * TCOLS * CELLU)   // 3520 uints = 14080 B per buffer
#define NEG_INF_F (-1e30f)

typedef _Float16 h2v __attribute__((ext_vector_type(2)));
typedef __fp16   p2v __attribute__((ext_vector_type(2)));   // cvt_pkrtz result type

#define FDOT2(a, b, c) __builtin_amdgcn_fdot2((a), (b), (c), false)

union CV { p2v p; h2v h; uint u; };
union U4 { int4 v; uint u[4]; h2v h[4]; };

// acc(f32) += f16 half of vu * f16 half of pu — one v_fma_mix_f32.
#define FMIX(acc, vu, vh, pu, ph) do {                                                                              \
    if      ((vh) == 0 && (ph) == 0) asm("v_fma_mix_f32 %0, %1, %2, %0 op_sel:[0,0,0] op_sel_hi:[1,1,0]" : "+v"(acc) : "v"(vu), "v"(pu)); \
    else if ((vh) == 1 && (ph) == 0) asm("v_fma_mix_f32 %0, %1, %2, %0 op_sel:[1,0,0] op_sel_hi:[1,1,0]" : "+v"(acc) : "v"(vu), "v"(pu)); \
    else if ((vh) == 0 && (ph) == 1) asm("v_fma_mix_f32 %0, %1, %2, %0 op_sel:[0,1,0] op_sel_hi:[1,1,0]" : "+v"(acc) : "v"(vu), "v"(pu)); \
    else                             asm("v_fma_mix_f32 %0, %1, %2, %0 op_sel:[1,1,0] op_sel_hi:[1,1,0]" : "+v"(acc) : "v"(vu), "v"(pu)); \
} while (0)

// ---------------------------------------------------------------------------
// Pack W (Ch x Cin) -> pair-interleaved f16 for v_dot2; resolve same_WqWk.
// ---------------------------------------------------------------------------
__global__ __launch_bounds__(256) void wtrans_kernel(
    const float* __restrict__ Wq, const float* __restrict__ Wk,
    const int* __restrict__ same_flag,
    uint* __restrict__ WtPQ, uint* __restrict__ WtPK)
{
    const float* Wsel = (same_flag[0] != 0) ? Wq : Wk;
    for (int idx = threadIdx.x; idx < (CIN / 2) * CH; idx += 256) {
        int i2 = idx >> 6;
        int o  = idx & 63;
        CV a; a.p = __builtin_amdgcn_cvt_pkrtz(Wq[o * CIN + 2 * i2], Wq[o * CIN + 2 * i2 + 1]);
        WtPQ[idx] = a.u;
        CV b2; b2.p = __builtin_amdgcn_cvt_pkrtz(Wsel[o * CIN + 2 * i2], Wsel[o * CIN + 2 * i2 + 1]);
        WtPK[idx] = b2.u;
    }
}

// ---------------------------------------------------------------------------
// Convs: y=0 computes BOTH Q and K_left from one pass over left (left fetched
// once from HBM); y=1 computes K_right. v_dot2_f32_f16, pair-packed outputs.
// (256,3): ~168-VGPR budget so acc_q[64]+acc_k[64] stay in VGPRs.
// ---------------------------------------------------------------------------
__global__ __launch_bounds__(256, 3) void conv_kernel(
    const float* __restrict__ left, const float* __restrict__ right,
    const uint* __restrict__ WtPQ, const uint* __restrict__ WtPK,
    const float* __restrict__ bq, const float* __restrict__ bk,
    const int* __restrict__ same_flag,
    uint* __restrict__ dQ, uint* __restrict__ dKL, uint* __restrict__ dKR)
{
    int b  = blockIdx.x >> 2;
    int px = ((blockIdx.x & 3) << 8) + threadIdx.x;
    const float* biasK = (same_flag[0] != 0) ? bq : bk;

    if (blockIdx.y == 0) {
        const float* xb = left + (size_t)b * (CIN * NPX) + px;
        float aq[CH], ak[CH];
#pragma unroll
        for (int o = 0; o < CH; ++o) { aq[o] = bq[o]; ak[o] = biasK[o]; }
#pragma unroll 2
        for (int i2 = 0; i2 < CIN / 2; ++i2) {
            float x0 = xb[(size_t)(2 * i2) << 10];
            float x1 = xb[(size_t)(2 * i2 + 1) << 10];
            CV xp; xp.p = __builtin_amdgcn_cvt_pkrtz(x0, x1);
            const uint* wq = WtPQ + (i2 << 6);
            const uint* wk = WtPK + (i2 << 6);
#pragma unroll
            for (int o = 0; o < CH; ++o) {
                CV wv; wv.u = wq[o];
                aq[o] = FDOT2(xp.h, wv.h, aq[o]);
                CV kv; kv.u = wk[o];
                ak[o] = FDOT2(xp.h, kv.h, ak[o]);
            }
        }
        uint* dbq = dQ  + (size_t)b * ((CH / 2) * NPX) + px;
        uint* dbk = dKL + (size_t)b * ((CH / 2) * NPX) + px;
#pragma unroll
        for (int o2 = 0; o2 < CH / 2; ++o2) {
            CV cq; cq.p = __builtin_amdgcn_cvt_pkrtz(aq[2 * o2], aq[2 * o2 + 1]);
            dbq[(size_t)o2 << 10] = cq.u;
            CV ck; ck.p = __builtin_amdgcn_cvt_pkrtz(ak[2 * o2], ak[2 * o2 + 1]);
            dbk[(size_t)o2 << 10] = ck.u;
        }
    } else {
        const float* xb = right + (size_t)b * (CIN * NPX) + px;
        float ak[CH];
#pragma unroll
        for (int o = 0; o < CH; ++o) ak[o] = biasK[o];
#pragma unroll 4
        for (int i2 = 0; i2 < CIN / 2; ++i2) {
            float x0 = xb[(size_t)(2 * i2) << 10];
            float x1 = xb[(size_t)(2 * i2 + 1) << 10];
            CV xp; xp.p = __builtin_amdgcn_cvt_pkrtz(x0, x1);
            const uint* wk = WtPK + (i2 << 6);
#pragma unroll
            for (int o = 0; o < CH; ++o) {
                CV kv; kv.u = wk[o];
                ak[o] = FDOT2(xp.h, kv.h, ak[o]);
            }
        }
        uint* dbk = dKR + (size_t)b * ((CH / 2) * NPX) + px;
#pragma unroll
        for (int o2 = 0; o2 < CH / 2; ++o2) {
            CV ck; ck.p = __builtin_amdgcn_cvt_pkrtz(ak[2 * o2], ak[2 * o2 + 1]);
            dbk[(size_t)o2 << 10] = ck.u;
        }
    }
}

// ---------------------------------------------------------------------------
// Merged fused local attention (sides via blockIdx.y). 16-row tile, 2 vertical
// px/thread, shared taps in both phases (sc0+sc1 both live; (256,3) gives the
// register room). Double-buffered, register-PREFETCHED staging: global loads
// for the next group issue one full compute-phase ahead of their ds_write.
// All LDS cells are 8ch x f16 = 16 B (8-way aliasing = b128 data-path min).
// ---------------------------------------------------------------------------
__global__ __launch_bounds__(256, 3) void attend2_kernel(
    const uint* __restrict__ Q, const uint* __restrict__ KR,
    const uint* __restrict__ KL,
    const float* __restrict__ right, const float* __restrict__ left,
    float* __restrict__ out, const int* __restrict__ self_flag)
{
    __shared__ __align__(16) uint buf[2 * BUFU];   // 28160 B

    int side = blockIdx.y;            // 0: right-attend, 1: left-attend
    int b    = blockIdx.x >> 1;
    int h0   = (blockIdx.x & 1) << 4;
    int t    = threadIdx.x;
    int w    = t & 31;
    int r2   = (t >> 5) << 1;         // 0,2,..,14
    int h    = h0 + r2;               // rows h and h+1
    int qoff = (h << 5) + w;
    int cb   = side ? 0 : CIN;

    const uint*  K = side ? KL : KR;
    const float* V = side ? left : right;

    if (side == 1 && self_flag[0] == 0) {
        const float* s = left + (size_t)b * (CIN * NPX) + qoff;
        float* d = out + (size_t)b * (2 * CIN * NPX) + qoff;
        for (int c = 0; c < CIN; ++c) {
            d[(size_t)c << 10] = s[(size_t)c << 10];
            d[((size_t)c << 10) + 32] = s[((size_t)c << 10) + 32];
        }
        return;
    }

    // ---- zero both buffers once (borders stay 0 through A and C) ----
#pragma unroll
    for (int i = 0; i < 7; ++i) {
        int idx = t + (i << 8);
        if (idx < 2 * BUFU / 4) ((int4*)buf)[idx] = int4{0, 0, 0, 0};
    }

    int rowlo = (h0 == 0) ? 0 : h0 - 3;   // first valid global row (19 staged)
    int rowof = (h0 == 0) ? 3 : 0;        // its LDS row
    int c2    = (t >> 5) & 3;             // staging channel-pair within group
    int rr    = t >> 7;                   // staging row parity

    const uint* Kb = K + (size_t)b * ((CH / 2) * NPX);
    const uint* Qb = Q + (size_t)b * ((CH / 2) * NPX);

    float sc0[NWIN], sc1[NWIN];
#pragma unroll
    for (int i = 0; i < NWIN; ++i) { sc0[i] = 0.f; sc1[i] = 0.f; }

#define ROWS_OK(i) (rr + 2 * (i) < 19)
#define PFK(g, arr)                                                            \
    _Pragma("unroll") for (int i = 0; i < 10; ++i) if (ROWS_OK(i))             \
        arr[i] = Kb[((size_t)((((g) << 2) + c2)) << 10) + ((rowlo + rr + 2 * i) << 5) + w];
#define WRK(bp, arr)                                                           \
    _Pragma("unroll") for (int i = 0; i < 10; ++i) if (ROWS_OK(i))             \
        (bp)[((rowof + rr + 2 * i) * TCOLS + (w + 4)) * CELLU + c2] = arr[i];

#define COMPA(bp, g) {                                                         \
    CV qa[4], qc[4];                                                           \
    _Pragma("unroll") for (int j = 0; j < 4; ++j) {                            \
        qa[j].u = Qb[((size_t)(((g) << 2) + j) << 10) + qoff];                 \
        qc[j].u = Qb[((size_t)(((g) << 2) + j) << 10) + qoff + 32];            \
    }                                                                          \
    _Pragma("unroll") for (int dh = 0; dh < 8; ++dh) {                         \
        int cu0 = ((r2 + dh) * TCOLS + (w + 1)) * CELLU;                       \
        _Pragma("unroll") for (int dw = 0; dw < 7; ++dw) {                     \
            U4 kk; kk.v = *(const int4*)((bp) + cu0 + dw * CELLU);             \
            if (dh < 7) {                                                      \
                float s = sc0[dh * 7 + dw];                                    \
                _Pragma("unroll") for (int j = 0; j < 4; ++j)                  \
                    s = FDOT2(kk.h[j], qa[j].h, s);                            \
                sc0[dh * 7 + dw] = s;                                          \
            }                                                                  \
            if (dh >= 1) {                                                     \
                float s = sc1[(dh - 1) * 7 + dw];                              \
                _Pragma("unroll") for (int j = 0; j < 4; ++j)                  \
                    s = FDOT2(kk.h[j], qc[j].h, s);                            \
                sc1[(dh - 1) * 7 + dw] = s;                                    \
            }                                                                  \
        }                                                                      \
    } }

    // ---- Phase A: 8 groups of 8 ch, processed in dbuf pairs ----
    {
        uint pfa[10], pfb[10];
        PFK(0, pfa); PFK(1, pfb);
#pragma unroll 1
        for (int gp = 0; gp < 4; ++gp) {
            __syncthreads();                 // prior compute / zero-fill done
            WRK(buf, pfa); WRK(buf + BUFU, pfb);
            if (gp < 3) { PFK(2 * gp + 2, pfa); PFK(2 * gp + 3, pfb); }
            __syncthreads();                 // staged data visible
            COMPA(buf, 2 * gp);
            COMPA(buf + BUFU, 2 * gp + 1);
        }
    }

    // ---- masked softmax per pixel; weights packed to f16 pairs ----
    uint ph0[25], ph1[25];
    {
        float m = NEG_INF_F;
#pragma unroll
        for (int dh = 0; dh < 7; ++dh)
#pragma unroll
            for (int dw = 0; dw < 7; ++dw) {
                int i = dh * 7 + dw;
                bool vld = ((unsigned)(h + dh - 3) < 32u) && ((unsigned)(w + dw - 3) < 32u);
                sc0[i] = vld ? sc0[i] : NEG_INF_F;
                m = fmaxf(m, sc0[i]);
            }
        float ssum = 0.f;
#pragma unroll
        for (int i = 0; i < NWIN; ++i) { sc0[i] = __expf(sc0[i] - m); ssum += sc0[i]; }
        float inv = 1.f / ssum;
#pragma unroll
        for (int j = 0; j < 24; ++j) {
            CV cv; cv.p = __builtin_amdgcn_cvt_pkrtz(sc0[2 * j] * inv, sc0[2 * j + 1] * inv);
            ph0[j] = cv.u;
        }
        CV cv; cv.p = __builtin_amdgcn_cvt_pkrtz(sc0[48] * inv, 0.f);
        ph0[24] = cv.u;
    }
    {
        float m = NEG_INF_F;
#pragma unroll
        for (int dh = 0; dh < 7; ++dh)
#pragma unroll
            for (int dw = 0; dw < 7; ++dw) {
                int i = dh * 7 + dw;
                bool vld = ((unsigned)(h + 1 + dh - 3) < 32u) && ((unsigned)(w + dw - 3) < 32u);
                sc1[i] = vld ? sc1[i] : NEG_INF_F;
                m = fmaxf(m, sc1[i]);
            }
        float ssum = 0.f;
#pragma unroll
        for (int i = 0; i < NWIN; ++i) { sc1[i] = __expf(sc1[i] - m); ssum += sc1[i]; }
        float inv = 1.f / ssum;
#pragma unroll
        for (int j = 0; j < 24; ++j) {
            CV cv; cv.p = __builtin_amdgcn_cvt_pkrtz(sc1[2 * j] * inv, sc1[2 * j + 1] * inv);
            ph1[j] = cv.u;
        }
        CV cv; cv.p = __builtin_amdgcn_cvt_pkrtz(sc1[48] * inv, 0.f);
        ph1[24] = cv.u;
    }

    // ---- Phase C: 16 groups of 8 ch, prefetched f32 V, shared taps ----
    const float* Vb = V + (size_t)b * (CIN * NPX);
    float* ob = out + (size_t)b * (2 * CIN * NPX) + ((size_t)cb << 10) + qoff;

    float pv0[10], pv1[10];
#define PFV(vg) {                                                              \
    const float* va = Vb + ((size_t)((((vg) << 2) + c2) * 2) << 10);           \
    const float* vc = va + NPX;                                                \
    _Pragma("unroll") for (int i = 0; i < 10; ++i) if (ROWS_OK(i)) {           \
        int gi = ((rowlo + rr + 2 * i) << 5) + w;                              \
        pv0[i] = va[gi]; pv1[i] = vc[gi];                                      \
    } }

    PFV(0);
#pragma unroll 1
    for (int vg = 0; vg < 16; ++vg) {
        __syncthreads();                     // prior reads of buf done
#pragma unroll
        for (int i = 0; i < 10; ++i) if (ROWS_OK(i)) {
            CV cv; cv.p = __builtin_amdgcn_cvt_pkrtz(pv0[i], pv1[i]);
            buf[((rowof + rr + 2 * i) * TCOLS + (w + 4)) * CELLU + c2] = cv.u;
        }
        if (vg < 15) PFV(vg + 1);
        __syncthreads();                     // staged data visible

        float a0[8], a1[8];
#pragma unroll
        for (int c = 0; c < 8; ++c) { a0[c] = 0.f; a1[c] = 0.f; }

#pragma unroll
        for (int dh = 0; dh < 8; ++dh) {
            int cu0 = ((r2 + dh) * TCOLS + (w + 1)) * CELLU;
#pragma unroll
            for (int dw = 0; dw < 7; ++dw) {
                U4 kk; kk.v = *(const int4*)(buf + cu0 + dw * CELLU);
                if (dh < 7) {
                    int tp = dh * 7 + dw;
#pragma unroll
                    for (int c = 0; c < 8; ++c)
                        FMIX(a0[c], kk.u[c >> 1], (c & 1), ph0[tp >> 1], (tp & 1));
                }
                if (dh >= 1) {
                    int tp = (dh - 1) * 7 + dw;
#pragma unroll
                    for (int c = 0; c < 8; ++c)
                        FMIX(a1[c], kk.u[c >> 1], (c & 1), ph1[tp >> 1], (tp & 1));
                }
            }
        }
#pragma unroll
        for (int c = 0; c < 8; ++c) {
            ob[((size_t)((vg << 3) + c)) << 10] = a0[c];
            ob[(((size_t)((vg << 3) + c)) << 10) + 32] = a1[c];
        }
    }
}

// ---------------------------------------------------------------------------
// 3 launches: wtrans -> conv (2048 blocks) -> attend2 (1024 blocks).
// ws: 3 x 32 MiB pair-packed f16 (Q, K_left, K_right) + 2 packed W = 96.03 MiB.
// ---------------------------------------------------------------------------
extern "C" void kernel_launch(void* const* d_in, const int* in_sizes, int n_in,
                              void* d_out, int out_size, void* d_ws, size_t ws_size,
                              hipStream_t stream)
{
    (void)in_sizes; (void)n_in; (void)out_size; (void)ws_size;

    const float* left  = (const float*)d_in[0];
    const float* right = (const float*)d_in[1];
    const float* Wq    = (const float*)d_in[2];
    const float* bq    = (const float*)d_in[3];
    const float* Wk    = (const float*)d_in[4];
    const float* bk    = (const float*)d_in[5];
    const int* self_flag = (const int*)d_in[7];
    const int* same_flag = (const int*)d_in[8];

    uint* wsQ  = (uint*)d_ws;                              // 32 MiB
    uint* wsKL = wsQ  + (size_t)B_ * (CH / 2) * NPX;       // 32 MiB
    uint* wsKR = wsKL + (size_t)B_ * (CH / 2) * NPX;       // 32 MiB
    uint* WtPQ = wsKR + (size_t)B_ * (CH / 2) * NPX;       // 4096 uints
    uint* WtPK = WtPQ + (CIN / 2) * CH;

    float* out = (float*)d_out;

    wtrans_kernel<<<1, 256, 0, stream>>>(Wq, Wk, same_flag, WtPQ, WtPK);

    conv_kernel<<<dim3(B_ * 4, 2), 256, 0, stream>>>(
        left, right, WtPQ, WtPK, bq, bk, same_flag, wsQ, wsKL, wsKR);

    attend2_kernel<<<dim3(B_ * 2, 2), 256, 0, stream>>>(
        wsQ, wsKR, wsKL, right, left, out, self_flag);
}